// Round 3
// baseline (634.735 us; speedup 1.0000x reference)
//
#include <hip/hip_runtime.h>

#define T_STEPS 512
#define B_TOT   1024
#define HID     128
#define NB      4      // batch lanes per block
#define NWAVE   8

typedef __bf16 bf16x8 __attribute__((ext_vector_type(8)));
typedef float  f32x4  __attribute__((ext_vector_type(4)));

__device__ __forceinline__ float sigm_f(float x) {
  return __builtin_amdgcn_rcpf(1.f + __expf(-x));
}
__device__ __forceinline__ float tanh_f(float x) {
  return 1.f - 2.f * __builtin_amdgcn_rcpf(1.f + __expf(2.f * x));
}

#define MFMA16(a, b, c) __builtin_amdgcn_mfma_f32_16x16x32_bf16((a), (b), (c), 0, 0, 0)

// Layouts (v_mfma_f32_16x16x32_bf16):
//   A (16x32): row = lane&15, k = (lane>>4)*8 + j   (j = 0..7 contiguous)
//   B (32x16): col = lane&15, k = (lane>>4)*8 + j
//   D (16x16): col = lane&15, row = (lane>>4)*4 + r  (r = acc reg)   [m89-verified]
__global__ __launch_bounds__(512, 2)
void lstm_bkt_kernel(const float* __restrict__ x, const float* __restrict__ y,
                     const float* __restrict__ W_ih, const float* __restrict__ W_hh,
                     const float* __restrict__ b_ih, const float* __restrict__ b_hh,
                     const float* __restrict__ prior_W, const float* __restrict__ prior_b,
                     const float* __restrict__ post_W, const float* __restrict__ post_b,
                     float* __restrict__ out)
{
  __shared__ __align__(16) __bf16 h_lds[2][NB][136];          // 136 = 128 + pad (bank spread)
  __shared__ __align__(16) float  gates_lds[NB][520];          // 520 = 512 + pad
  __shared__ __align__(16) float  x_lds[T_STEPS][NB];
  __shared__ __align__(16) float  params_lds[T_STEPS][NB][4];  // raw logits, later sigmoid, later corrects
  __shared__ float wsums[NWAVE];

  const int tid  = threadIdx.x;
  const int wave = tid >> 6;
  const int lane = tid & 63;
  const int b0   = blockIdx.x * NB;

  // stage x for this block's batch lanes
  for (int idx = tid; idx < T_STEPS * NB; idx += 512) {
    x_lds[idx >> 2][idx & 3] = x[(idx >> 2) * B_TOT + b0 + (idx & 3)];
  }

  const int arow = lane & 15;
  const int kgrp = lane >> 4;

  // W_hh as register-resident A-fragments, hi+lo bf16 split.
  // Wave w owns gate rows q*128 + w*16 + [0,16) for q=i,f,g,o.
  bf16x8 a_hi[4][4], a_lo[4][4];
#pragma unroll
  for (int q = 0; q < 4; ++q) {
#pragma unroll
    for (int kt = 0; kt < 4; ++kt) {
      const float* p = W_hh + (q * HID + wave * 16 + arow) * HID + kt * 32 + kgrp * 8;
      f32x4 v0 = *(const f32x4*)(p);
      f32x4 v1 = *(const f32x4*)(p + 4);
      bf16x8 hi, lo;
#pragma unroll
      for (int j = 0; j < 4; ++j) {
        __bf16 h1 = (__bf16)v0[j];
        hi[j] = h1; lo[j] = (__bf16)(v0[j] - (float)h1);
        __bf16 h2 = (__bf16)v1[j];
        hi[4 + j] = h2; lo[4 + j] = (__bf16)(v1[j] - (float)h2);
      }
      a_hi[q][kt] = hi; a_lo[q][kt] = lo;
    }
  }

  // post_W (4x128) as a 5th M-tile (rows 0..3 valid, rest zero). Used by wave 7 only.
  bf16x8 ap[4];
#pragma unroll
  for (int kt = 0; kt < 4; ++kt) {
    bf16x8 v;
#pragma unroll
    for (int j = 0; j < 8; ++j) v[j] = (__bf16)0.f;
    if (arow < 4) {
      const float* p = post_W + arow * HID + kt * 32 + kgrp * 8;
#pragma unroll
      for (int j = 0; j < 8; ++j) v[j] = (__bf16)p[j];
    }
    ap[kt] = v;
  }

  // epilogue: one (batch, hid) pair per lane
  const int b_e   = tid >> 7;    // 0..3  (wave-uniform)
  const int hid_e = tid & 127;
  float wih[4], bias[4];
#pragma unroll
  for (int q = 0; q < 4; ++q) {
    wih[q]  = W_ih[q * HID + hid_e];
    bias[q] = b_ih[q * HID + hid_e] + b_hh[q * HID + hid_e];
  }

  float c_state = 0.f;
  int cur = 0;

  __syncthreads();

  // iter k uses h_state_k (h_state_0 = 0 -> MFMA skipped at k=0).
  // MFMA at iter k also yields post_W@h_state_k = logits for params[k-1].
  for (int k = 0; k <= T_STEPS; ++k) {
    f32x4 acc0 = {0.f, 0.f, 0.f, 0.f};
    f32x4 acc1 = acc0, acc2 = acc0, acc3 = acc0, accp = acc0;

    if (k > 0) {
      const int nsel = lane & 3;     // cols 4..15 are duplicates, ignored on store
      bf16x8 bfr[4];
#pragma unroll
      for (int kt = 0; kt < 4; ++kt)
        bfr[kt] = *(const bf16x8*)&h_lds[cur][nsel][kt * 32 + kgrp * 8];
#pragma unroll
      for (int kt = 0; kt < 4; ++kt) {
        acc0 = MFMA16(a_hi[0][kt], bfr[kt], acc0);
        acc1 = MFMA16(a_hi[1][kt], bfr[kt], acc1);
        acc2 = MFMA16(a_hi[2][kt], bfr[kt], acc2);
        acc3 = MFMA16(a_hi[3][kt], bfr[kt], acc3);
        acc0 = MFMA16(a_lo[0][kt], bfr[kt], acc0);
        acc1 = MFMA16(a_lo[1][kt], bfr[kt], acc1);
        acc2 = MFMA16(a_lo[2][kt], bfr[kt], acc2);
        acc3 = MFMA16(a_lo[3][kt], bfr[kt], acc3);
        if (wave == 7) accp = MFMA16(ap[kt], bfr[kt], accp);
      }
    }

    if (k < T_STEPS && (lane & 15) < 4) {
      const int n = lane & 15;
      *(f32x4*)&gates_lds[n][0 * HID + wave * 16 + kgrp * 4] = acc0;
      *(f32x4*)&gates_lds[n][1 * HID + wave * 16 + kgrp * 4] = acc1;
      *(f32x4*)&gates_lds[n][2 * HID + wave * 16 + kgrp * 4] = acc2;
      *(f32x4*)&gates_lds[n][3 * HID + wave * 16 + kgrp * 4] = acc3;
    }
    if (k > 0 && wave == 7 && lane < 4) {
      *(f32x4*)&params_lds[k - 1][lane][0] = accp;   // rows 0..3 = p, col = lane = n
    }
    __syncthreads();

    if (k < T_STEPS) {
      const float xv = x_lds[k][b_e];
      float gi = gates_lds[b_e][0 * HID + hid_e] + xv * wih[0] + bias[0];
      float gf = gates_lds[b_e][1 * HID + hid_e] + xv * wih[1] + bias[1];
      float gg = gates_lds[b_e][2 * HID + hid_e] + xv * wih[2] + bias[2];
      float go = gates_lds[b_e][3 * HID + hid_e] + xv * wih[3] + bias[3];
      float is = sigm_f(gi), fs = sigm_f(gf), gt = tanh_f(gg), os = sigm_f(go);
      c_state = fs * c_state + is * gt;
      float h = os * tanh_f(c_state);
      h_lds[cur ^ 1][b_e][hid_e] = (__bf16)h;
    }
    __syncthreads();
    cur ^= 1;
  }

  // params: + post_b, sigmoid (all 512 threads, 16 elems each)
  {
    const float pb0 = post_b[0], pb1 = post_b[1], pb2 = post_b[2], pb3 = post_b[3];
    float* pl = &params_lds[0][0][0];
    for (int idx = tid; idx < T_STEPS * NB * 4; idx += 512) {
      const int p = idx & 3;
      const float pb = (p == 0) ? pb0 : (p == 1) ? pb1 : (p == 2) ? pb2 : pb3;
      pl[idx] = sigm_f(pl[idx] + pb);
    }
  }
  __syncthreads();

  // BKT scan. m_t algebraically == latent, so the recursion is affine:
  //   correct = L*(1-s-g)+g ;  next_L = L*(1-f-l)+l
  if (tid < NB) {
    const int n = tid;
    float L = sigm_f(x_lds[0][n] * prior_W[0] + prior_b[0]);
    float* cor_out = out;
    float* lat_out = out + T_STEPS * B_TOT;
    for (int t = 0; t < T_STEPS; ++t) {
      f32x4 p = *(const f32x4*)&params_lds[t][n][0];   // l,f,g,s
      float corr = L * (1.f - p[3] - p[2]) + p[2];
      float nL   = L * (1.f - p[1] - p[0]) + p[0];
      cor_out[t * B_TOT + b0 + n] = corr;
      lat_out[t * B_TOT + b0 + n] = nL;
      params_lds[t][n][0] = corr;                      // stash for BCE
      L = nL;
    }
  }
  __syncthreads();

  // BCE loss: parallel over (t,n), block-reduce, one atomic per block
  float lsum = 0.f;
  for (int idx = tid; idx < T_STEPS * NB; idx += 512) {
    const int t = idx >> 2, n = idx & 3;
    const float corr = params_lds[t][n][0];
    const float yv = y[t * B_TOT + b0 + n];
    const float lc  = fmaxf(__logf(corr), -100.f);
    const float lc1 = fmaxf(__logf(1.f - corr), -100.f);
    lsum -= yv * lc + (1.f - yv) * lc1;
  }
#pragma unroll
  for (int off = 32; off > 0; off >>= 1) lsum += __shfl_down(lsum, off, 64);
  if (lane == 0) wsums[wave] = lsum;
  __syncthreads();
  if (tid == 0) {
    float s = 0.f;
#pragma unroll
    for (int w = 0; w < NWAVE; ++w) s += wsums[w];
    atomicAdd(out + 2 * T_STEPS * B_TOT, s * (1.f / (float)(T_STEPS * B_TOT)));
  }
}

__global__ void loss_init_kernel(float* out) {
  out[2 * T_STEPS * B_TOT] = 0.f;
}

extern "C" void kernel_launch(void* const* d_in, const int* in_sizes, int n_in,
                              void* d_out, int out_size, void* d_ws, size_t ws_size,
                              hipStream_t stream) {
  (void)in_sizes; (void)n_in; (void)out_size; (void)d_ws; (void)ws_size;
  const float* x       = (const float*)d_in[0];
  const float* y       = (const float*)d_in[1];
  const float* W_ih    = (const float*)d_in[2];
  const float* W_hh    = (const float*)d_in[3];
  const float* b_ih    = (const float*)d_in[4];
  const float* b_hh    = (const float*)d_in[5];
  const float* prior_W = (const float*)d_in[6];
  const float* prior_b = (const float*)d_in[7];
  const float* post_W  = (const float*)d_in[8];
  const float* post_b  = (const float*)d_in[9];
  float* out = (float*)d_out;

  loss_init_kernel<<<dim3(1), dim3(1), 0, stream>>>(out);
  lstm_bkt_kernel<<<dim3(B_TOT / NB), dim3(512), 0, stream>>>(
      x, y, W_ih, W_hh, b_ih, b_hh, prior_W, prior_b, post_W, post_b, out);
}

// Round 4
// 584.160 us; speedup vs baseline: 1.0866x; 1.0866x over previous
//
#include <hip/hip_runtime.h>

#define T_STEPS 512
#define B_TOT   1024
#define HID     128
#define NB      4      // batch lanes per block
#define NWAVE   8

typedef __bf16 bf16x8 __attribute__((ext_vector_type(8)));
typedef float  f32x4  __attribute__((ext_vector_type(4)));

__device__ __forceinline__ float sigm_f(float x) {
  return __builtin_amdgcn_rcpf(1.f + __expf(-x));
}
__device__ __forceinline__ float tanh_f(float x) {
  return 1.f - 2.f * __builtin_amdgcn_rcpf(1.f + __expf(2.f * x));
}

#define MFMA16(a, b, c) __builtin_amdgcn_mfma_f32_16x16x32_bf16((a), (b), (c), 0, 0, 0)

// Layouts (v_mfma_f32_16x16x32_bf16):
//   A (16x32): row = lane&15, k = (lane>>4)*8 + j
//   B (32x16): col = lane&15, k = (lane>>4)*8 + j
//   D (16x16): col = lane&15, row = (lane>>4)*4 + r   [m89-verified]
// B col c is fed from h[batch c&3] -> D col c = gates for batch c&3 (4x dup).
// Lane (l) epilogue target: batch n=l&3, r-slot j=(l>>2)&3, hid = wave*16+(l>>4)*4+j.
// => every (n,hid) covered exactly once per wave; all 4 gates in-lane. No gates LDS.
__global__ __launch_bounds__(512, 2)
void lstm_bkt_kernel(const float* __restrict__ x, const float* __restrict__ y,
                     const float* __restrict__ W_ih, const float* __restrict__ W_hh,
                     const float* __restrict__ b_ih, const float* __restrict__ b_hh,
                     const float* __restrict__ prior_W, const float* __restrict__ prior_b,
                     const float* __restrict__ post_W, const float* __restrict__ post_b,
                     float* __restrict__ out)
{
  __shared__ __align__(16) __bf16 h_lds[2][NB][136];           // 136 = 128 + pad
  __shared__ __align__(16) float  x_lds[T_STEPS][NB];
  __shared__ __align__(16) float  params_lds[T_STEPS][NB][4];  // logits -> sigmoid -> corrects
  __shared__ float wsums[NWAVE];

  const int tid  = threadIdx.x;
  const int wave = tid >> 6;
  const int lane = tid & 63;
  const int b0   = blockIdx.x * NB;

  // stage x for this block's batch lanes
  for (int idx = tid; idx < T_STEPS * NB; idx += 512) {
    x_lds[idx >> 2][idx & 3] = x[(idx >> 2) * B_TOT + b0 + (idx & 3)];
  }

  const int arow = lane & 15;
  const int kgrp = lane >> 4;

  // W_hh register-resident A-fragments, hi+lo bf16 split.
  bf16x8 a_hi[4][4], a_lo[4][4];
#pragma unroll
  for (int q = 0; q < 4; ++q) {
#pragma unroll
    for (int kt = 0; kt < 4; ++kt) {
      const float* p = W_hh + (q * HID + wave * 16 + arow) * HID + kt * 32 + kgrp * 8;
      f32x4 v0 = *(const f32x4*)(p);
      f32x4 v1 = *(const f32x4*)(p + 4);
      bf16x8 hi, lo;
#pragma unroll
      for (int j = 0; j < 4; ++j) {
        __bf16 h1 = (__bf16)v0[j];
        hi[j] = h1; lo[j] = (__bf16)(v0[j] - (float)h1);
        __bf16 h2 = (__bf16)v1[j];
        hi[4 + j] = h2; lo[4 + j] = (__bf16)(v1[j] - (float)h2);
      }
      a_hi[q][kt] = hi; a_lo[q][kt] = lo;
    }
  }

  // post_W (4x128) as a 5th M-tile (rows 0..3 valid). Wave 7 only.
  bf16x8 ap[4];
#pragma unroll
  for (int kt = 0; kt < 4; ++kt) {
    bf16x8 v;
#pragma unroll
    for (int j = 0; j < 8; ++j) v[j] = (__bf16)0.f;
    if (arow < 4) {
      const float* p = post_W + arow * HID + kt * 32 + kgrp * 8;
#pragma unroll
      for (int j = 0; j < 8; ++j) v[j] = (__bf16)p[j];
    }
    ap[kt] = v;
  }

  // in-register epilogue assignment (one (batch,hid) per lane)
  const int n_l   = lane & 3;
  const int j_l   = (lane >> 2) & 3;
  const int hid_l = wave * 16 + kgrp * 4 + j_l;
  float wih[4], bias[4];
#pragma unroll
  for (int q = 0; q < 4; ++q) {
    wih[q]  = W_ih[q * HID + hid_l];
    bias[q] = b_ih[q * HID + hid_l] + b_hh[q * HID + hid_l];
  }

  float c_state = 0.f;
  int cur = 0;

  __syncthreads();

  // iter k: B input = h_state_k (h_0 = 0 -> MFMA skipped at k=0).
  // wave7's accp at iter k = post_W @ h_k = logits for params[k-1].
  for (int k = 0; k <= T_STEPS; ++k) {
    f32x4 a0h = {0.f, 0.f, 0.f, 0.f};
    f32x4 a1h = a0h, a2h = a0h, a3h = a0h;
    f32x4 a0l = a0h, a1l = a0h, a2l = a0h, a3l = a0h, accp = a0h;

    const float xv = (k < T_STEPS) ? x_lds[k][n_l] : 0.f;

    if (k > 0) {
      const int nsel = lane & 3;
      bf16x8 bfr[4];
#pragma unroll
      for (int kt = 0; kt < 4; ++kt)
        bfr[kt] = *(const bf16x8*)&h_lds[cur][nsel][kt * 32 + kgrp * 8];
#pragma unroll
      for (int kt = 0; kt < 4; ++kt) {
        a0h = MFMA16(a_hi[0][kt], bfr[kt], a0h);
        a1h = MFMA16(a_hi[1][kt], bfr[kt], a1h);
        a2h = MFMA16(a_hi[2][kt], bfr[kt], a2h);
        a3h = MFMA16(a_hi[3][kt], bfr[kt], a3h);
        a0l = MFMA16(a_lo[0][kt], bfr[kt], a0l);
        a1l = MFMA16(a_lo[1][kt], bfr[kt], a1l);
        a2l = MFMA16(a_lo[2][kt], bfr[kt], a2l);
        a3l = MFMA16(a_lo[3][kt], bfr[kt], a3l);
        if (wave == 7) accp = MFMA16(ap[kt], bfr[kt], accp);
      }
    }

    if (k > 0 && wave == 7 && lane < 4) {
      *(f32x4*)&params_lds[k - 1][lane][0] = accp;   // rows 0..3 = p, col = lane = n
    }

    if (k < T_STEPS) {
      // in-register gate gather: static-index select on j_l (rule #20 safe)
      f32x4 s0 = a0h + a0l, s1 = a1h + a1l, s2 = a2h + a2l, s3 = a3h + a3l;
      float g_i = (j_l == 0) ? s0[0] : (j_l == 1) ? s0[1] : (j_l == 2) ? s0[2] : s0[3];
      float g_f = (j_l == 0) ? s1[0] : (j_l == 1) ? s1[1] : (j_l == 2) ? s1[2] : s1[3];
      float g_g = (j_l == 0) ? s2[0] : (j_l == 1) ? s2[1] : (j_l == 2) ? s2[2] : s2[3];
      float g_o = (j_l == 0) ? s3[0] : (j_l == 1) ? s3[1] : (j_l == 2) ? s3[2] : s3[3];
      g_i += xv * wih[0] + bias[0];
      g_f += xv * wih[1] + bias[1];
      g_g += xv * wih[2] + bias[2];
      g_o += xv * wih[3] + bias[3];
      float is = sigm_f(g_i), fs = sigm_f(g_f), gt = tanh_f(g_g), os = sigm_f(g_o);
      c_state = fs * c_state + is * gt;
      float h = os * tanh_f(c_state);
      h_lds[cur ^ 1][n_l][hid_l] = (__bf16)h;
    }
    __syncthreads();
    cur ^= 1;
  }

  // params: + post_b, sigmoid
  {
    const float pb0 = post_b[0], pb1 = post_b[1], pb2 = post_b[2], pb3 = post_b[3];
    float* pl = &params_lds[0][0][0];
    for (int idx = tid; idx < T_STEPS * NB * 4; idx += 512) {
      const int p = idx & 3;
      const float pb = (p == 0) ? pb0 : (p == 1) ? pb1 : (p == 2) ? pb2 : pb3;
      pl[idx] = sigm_f(pl[idx] + pb);
    }
  }
  __syncthreads();

  // BKT scan: m_t == latent algebraically, so the recursion is affine:
  //   correct = L*(1-s-g)+g ;  next_L = L*(1-f-l)+l
  if (tid < NB) {
    const int n = tid;
    float L = sigm_f(x_lds[0][n] * prior_W[0] + prior_b[0]);
    float* cor_out = out;
    float* lat_out = out + T_STEPS * B_TOT;
    for (int t = 0; t < T_STEPS; ++t) {
      f32x4 p = *(const f32x4*)&params_lds[t][n][0];   // l,f,g,s
      float corr = L * (1.f - p[3] - p[2]) + p[2];
      float nL   = L * (1.f - p[1] - p[0]) + p[0];
      cor_out[t * B_TOT + b0 + n] = corr;
      lat_out[t * B_TOT + b0 + n] = nL;
      params_lds[t][n][0] = corr;                      // stash for BCE
      L = nL;
    }
  }
  __syncthreads();

  // BCE loss: parallel over (t,n), block-reduce, one atomic per block
  float lsum = 0.f;
  for (int idx = tid; idx < T_STEPS * NB; idx += 512) {
    const int t = idx >> 2, n = idx & 3;
    const float corr = params_lds[t][n][0];
    const float yv = y[t * B_TOT + b0 + n];
    const float lc  = fmaxf(__logf(corr), -100.f);
    const float lc1 = fmaxf(__logf(1.f - corr), -100.f);
    lsum -= yv * lc + (1.f - yv) * lc1;
  }
#pragma unroll
  for (int off = 32; off > 0; off >>= 1) lsum += __shfl_down(lsum, off, 64);
  if (lane == 0) wsums[wave] = lsum;
  __syncthreads();
  if (tid == 0) {
    float s = 0.f;
#pragma unroll
    for (int w = 0; w < NWAVE; ++w) s += wsums[w];
    atomicAdd(out + 2 * T_STEPS * B_TOT, s * (1.f / (float)(T_STEPS * B_TOT)));
  }
}

__global__ void loss_init_kernel(float* out) {
  out[2 * T_STEPS * B_TOT] = 0.f;
}

extern "C" void kernel_launch(void* const* d_in, const int* in_sizes, int n_in,
                              void* d_out, int out_size, void* d_ws, size_t ws_size,
                              hipStream_t stream) {
  (void)in_sizes; (void)n_in; (void)out_size; (void)d_ws; (void)ws_size;
  const float* x       = (const float*)d_in[0];
  const float* y       = (const float*)d_in[1];
  const float* W_ih    = (const float*)d_in[2];
  const float* W_hh    = (const float*)d_in[3];
  const float* b_ih    = (const float*)d_in[4];
  const float* b_hh    = (const float*)d_in[5];
  const float* prior_W = (const float*)d_in[6];
  const float* prior_b = (const float*)d_in[7];
  const float* post_W  = (const float*)d_in[8];
  const float* post_b  = (const float*)d_in[9];
  float* out = (float*)d_out;

  loss_init_kernel<<<dim3(1), dim3(1), 0, stream>>>(out);
  lstm_bkt_kernel<<<dim3(B_TOT / NB), dim3(512), 0, stream>>>(
      x, y, W_ih, W_hh, b_ih, b_hh, prior_W, prior_b, post_W, post_b, out);
}

// Round 5
// 526.269 us; speedup vs baseline: 1.2061x; 1.1100x over previous
//
#include <hip/hip_runtime.h>

#define T_STEPS 512
#define B_TOT   1024
#define HID     128
#define NB      4      // batch lanes per block
#define NWAVE   8

typedef __bf16 bf16x8 __attribute__((ext_vector_type(8)));
typedef float  f32x4  __attribute__((ext_vector_type(4)));

__device__ __forceinline__ float sigm_f(float x) {
  return __builtin_amdgcn_rcpf(1.f + __expf(-x));
}
__device__ __forceinline__ float tanh_f(float x) {
  return 1.f - 2.f * __builtin_amdgcn_rcpf(1.f + __expf(2.f * x));
}

#define MFMA16(a, b, c) __builtin_amdgcn_mfma_f32_16x16x32_bf16((a), (b), (c), 0, 0, 0)

// Layouts (v_mfma_f32_16x16x32_bf16):
//   A (16x32): row = lane&15, k = (lane>>4)*8 + j
//   B (32x16): col = lane&15, k = (lane>>4)*8 + j
//   D (16x16): col = lane&15, row = (lane>>4)*4 + r   [m89-verified]
// Lane l epilogue target: batch n=l&3, slot j=(l>>2)&3, hid = wave*16+(l>>4)*4+j.
// h_lds row stride 144 bf16 (288B): b128 read chunk bank = 8n+4kgrp -> 2-way (free).
// h write: shfl_xor pair-pack -> b32, banks 8n+2kgrp+j2 all distinct (conflict-free).
__global__ __launch_bounds__(512, 2)
void lstm_bkt_kernel(const float* __restrict__ x, const float* __restrict__ y,
                     const float* __restrict__ W_ih, const float* __restrict__ W_hh,
                     const float* __restrict__ b_ih, const float* __restrict__ b_hh,
                     const float* __restrict__ prior_W, const float* __restrict__ prior_b,
                     const float* __restrict__ post_W, const float* __restrict__ post_b,
                     float* __restrict__ out)
{
  __shared__ __align__(16) __bf16 h_lds[2][NB][144];           // 144 = 128 + 16 pad
  __shared__ __align__(16) float  x_lds[T_STEPS][NB];
  __shared__ __align__(16) float  params_lds[T_STEPS][NB][4];  // logits -> sigmoid -> corrects
  __shared__ float wsums[NWAVE];

  const int tid  = threadIdx.x;
  const int wave = tid >> 6;
  const int lane = tid & 63;
  const int b0   = blockIdx.x * NB;

  // stage x for this block's batch lanes
  for (int idx = tid; idx < T_STEPS * NB; idx += 512) {
    x_lds[idx >> 2][idx & 3] = x[(idx >> 2) * B_TOT + b0 + (idx & 3)];
  }

  const int arow = lane & 15;
  const int kgrp = lane >> 4;

  // W_hh register-resident A-fragments, hi+lo bf16 split.
  bf16x8 a_hi[4][4], a_lo[4][4];
#pragma unroll
  for (int q = 0; q < 4; ++q) {
#pragma unroll
    for (int kt = 0; kt < 4; ++kt) {
      const float* p = W_hh + (q * HID + wave * 16 + arow) * HID + kt * 32 + kgrp * 8;
      f32x4 v0 = *(const f32x4*)(p);
      f32x4 v1 = *(const f32x4*)(p + 4);
      bf16x8 hi, lo;
#pragma unroll
      for (int j = 0; j < 4; ++j) {
        __bf16 h1 = (__bf16)v0[j];
        hi[j] = h1; lo[j] = (__bf16)(v0[j] - (float)h1);
        __bf16 h2 = (__bf16)v1[j];
        hi[4 + j] = h2; lo[4 + j] = (__bf16)(v1[j] - (float)h2);
      }
      a_hi[q][kt] = hi; a_lo[q][kt] = lo;
    }
  }

  // post_W (4x128) as a 5th M-tile (rows 0..3 valid). Wave 7 only.
  bf16x8 ap[4];
#pragma unroll
  for (int kt = 0; kt < 4; ++kt) {
    bf16x8 v;
#pragma unroll
    for (int j = 0; j < 8; ++j) v[j] = (__bf16)0.f;
    if (arow < 4) {
      const float* p = post_W + arow * HID + kt * 32 + kgrp * 8;
#pragma unroll
      for (int j = 0; j < 8; ++j) v[j] = (__bf16)p[j];
    }
    ap[kt] = v;
  }

  // in-register epilogue assignment (one (batch,hid) per lane)
  const int n_l   = lane & 3;
  const int j_l   = (lane >> 2) & 3;
  const int hid_l = wave * 16 + kgrp * 4 + j_l;
  float wih[4], bias[4];
#pragma unroll
  for (int q = 0; q < 4; ++q) {
    wih[q]  = W_ih[q * HID + hid_l];
    bias[q] = b_ih[q * HID + hid_l] + b_hh[q * HID + hid_l];
  }

  const f32x4 fzero = {0.f, 0.f, 0.f, 0.f};
  float c_state = 0.f;
  int cur = 0;

  __syncthreads();

  // iter k: B input = h_state_k (h_0 = 0 -> MFMA skipped at k=0).
  // wave7's accp at iter k = post_W @ h_k = logits for params[k-1].
  for (int k = 0; k <= T_STEPS; ++k) {
    f32x4 a0 = fzero, a1 = fzero, a2 = fzero, a3 = fzero, accp = fzero;

    const float xv = (k < T_STEPS) ? x_lds[k][n_l] : 0.f;

    if (k > 0) {
      const int nsel = lane & 3;
      bf16x8 bfr[4];
#pragma unroll
      for (int kt = 0; kt < 4; ++kt)
        bfr[kt] = *(const bf16x8*)&h_lds[cur][nsel][kt * 32 + kgrp * 8];
      // first kt consumes fzero as C (no per-step acc zero-init)
      a0 = MFMA16(a_hi[0][0], bfr[0], fzero);
      a1 = MFMA16(a_hi[1][0], bfr[0], fzero);
      a2 = MFMA16(a_hi[2][0], bfr[0], fzero);
      a3 = MFMA16(a_hi[3][0], bfr[0], fzero);
      if (wave == 7) accp = MFMA16(ap[0], bfr[0], fzero);
#pragma unroll
      for (int kt = 1; kt < 4; ++kt) {
        a0 = MFMA16(a_hi[0][kt], bfr[kt], a0);
        a1 = MFMA16(a_hi[1][kt], bfr[kt], a1);
        a2 = MFMA16(a_hi[2][kt], bfr[kt], a2);
        a3 = MFMA16(a_hi[3][kt], bfr[kt], a3);
        if (wave == 7) accp = MFMA16(ap[kt], bfr[kt], accp);
      }
#pragma unroll
      for (int kt = 0; kt < 4; ++kt) {
        a0 = MFMA16(a_lo[0][kt], bfr[kt], a0);
        a1 = MFMA16(a_lo[1][kt], bfr[kt], a1);
        a2 = MFMA16(a_lo[2][kt], bfr[kt], a2);
        a3 = MFMA16(a_lo[3][kt], bfr[kt], a3);
      }
    }

    if (k > 0 && wave == 7 && lane < 4) {
      *(f32x4*)&params_lds[k - 1][lane][0] = accp;   // rows 0..3 = p, col = lane = n
    }

    if (k < T_STEPS) {
      // in-register gate gather: static-index select on j_l (rule #20 safe)
      float g_i = (j_l == 0) ? a0[0] : (j_l == 1) ? a0[1] : (j_l == 2) ? a0[2] : a0[3];
      float g_f = (j_l == 0) ? a1[0] : (j_l == 1) ? a1[1] : (j_l == 2) ? a1[2] : a1[3];
      float g_g = (j_l == 0) ? a2[0] : (j_l == 1) ? a2[1] : (j_l == 2) ? a2[2] : a2[3];
      float g_o = (j_l == 0) ? a3[0] : (j_l == 1) ? a3[1] : (j_l == 2) ? a3[2] : a3[3];
      g_i += xv * wih[0] + bias[0];
      g_f += xv * wih[1] + bias[1];
      g_g += xv * wih[2] + bias[2];
      g_o += xv * wih[3] + bias[3];
      float is = sigm_f(g_i), fs = sigm_f(g_f), gt = tanh_f(g_g), os = sigm_f(g_o);
      c_state = fs * c_state + is * gt;
      float h = os * tanh_f(c_state);
      // pair-pack h (hid, hid^1) via shfl_xor, even-j lanes write one b32 (conflict-free)
      unsigned hv = (unsigned)__builtin_bit_cast(unsigned short, (__bf16)h);
      unsigned pv = (unsigned)__shfl_xor((int)hv, 4, 64);
      if ((j_l & 1) == 0) {
        *(unsigned*)&h_lds[cur ^ 1][n_l][hid_l] = hv | (pv << 16);
      }
    }
    __syncthreads();
    cur ^= 1;
  }

  // params: + post_b, sigmoid
  {
    const float pb0 = post_b[0], pb1 = post_b[1], pb2 = post_b[2], pb3 = post_b[3];
    float* pl = &params_lds[0][0][0];
    for (int idx = tid; idx < T_STEPS * NB * 4; idx += 512) {
      const int p = idx & 3;
      const float pb = (p == 0) ? pb0 : (p == 1) ? pb1 : (p == 2) ? pb2 : pb3;
      pl[idx] = sigm_f(pl[idx] + pb);
    }
  }
  __syncthreads();

  // BKT scan: m_t == latent algebraically, so the recursion is affine:
  //   correct = L*(1-s-g)+g ;  next_L = L*(1-f-l)+l
  if (tid < NB) {
    const int n = tid;
    float L = sigm_f(x_lds[0][n] * prior_W[0] + prior_b[0]);
    float* cor_out = out;
    float* lat_out = out + T_STEPS * B_TOT;
    for (int t = 0; t < T_STEPS; ++t) {
      f32x4 p = *(const f32x4*)&params_lds[t][n][0];   // l,f,g,s
      float corr = L * (1.f - p[3] - p[2]) + p[2];
      float nL   = L * (1.f - p[1] - p[0]) + p[0];
      cor_out[t * B_TOT + b0 + n] = corr;
      lat_out[t * B_TOT + b0 + n] = nL;
      params_lds[t][n][0] = corr;                      // stash for BCE
      L = nL;
    }
  }
  __syncthreads();

  // BCE loss: parallel over (t,n), block-reduce, one atomic per block
  float lsum = 0.f;
  for (int idx = tid; idx < T_STEPS * NB; idx += 512) {
    const int t = idx >> 2, n = idx & 3;
    const float corr = params_lds[t][n][0];
    const float yv = y[t * B_TOT + b0 + n];
    const float lc  = fmaxf(__logf(corr), -100.f);
    const float lc1 = fmaxf(__logf(1.f - corr), -100.f);
    lsum -= yv * lc + (1.f - yv) * lc1;
  }
#pragma unroll
  for (int off = 32; off > 0; off >>= 1) lsum += __shfl_down(lsum, off, 64);
  if (lane == 0) wsums[wave] = lsum;
  __syncthreads();
  if (tid == 0) {
    float s = 0.f;
#pragma unroll
    for (int w = 0; w < NWAVE; ++w) s += wsums[w];
    atomicAdd(out + 2 * T_STEPS * B_TOT, s * (1.f / (float)(T_STEPS * B_TOT)));
  }
}

__global__ void loss_init_kernel(float* out) {
  out[2 * T_STEPS * B_TOT] = 0.f;
}

extern "C" void kernel_launch(void* const* d_in, const int* in_sizes, int n_in,
                              void* d_out, int out_size, void* d_ws, size_t ws_size,
                              hipStream_t stream) {
  (void)in_sizes; (void)n_in; (void)out_size; (void)d_ws; (void)ws_size;
  const float* x       = (const float*)d_in[0];
  const float* y       = (const float*)d_in[1];
  const float* W_ih    = (const float*)d_in[2];
  const float* W_hh    = (const float*)d_in[3];
  const float* b_ih    = (const float*)d_in[4];
  const float* b_hh    = (const float*)d_in[5];
  const float* prior_W = (const float*)d_in[6];
  const float* prior_b = (const float*)d_in[7];
  const float* post_W  = (const float*)d_in[8];
  const float* post_b  = (const float*)d_in[9];
  float* out = (float*)d_out;

  loss_init_kernel<<<dim3(1), dim3(1), 0, stream>>>(out);
  lstm_bkt_kernel<<<dim3(B_TOT / NB), dim3(512), 0, stream>>>(
      x, y, W_ih, W_hh, b_ih, b_hh, prior_W, prior_b, post_W, post_b, out);
}

// Round 8
// 417.688 us; speedup vs baseline: 1.5196x; 1.2600x over previous
//
#include <hip/hip_runtime.h>

#define T_STEPS 512
#define B_TOT   1024
#define HID     128
#define NB      4      // batch lanes per block
#define NWAVE   8

typedef __bf16 bf16x8 __attribute__((ext_vector_type(8)));
typedef float  f32x4  __attribute__((ext_vector_type(4)));

__device__ __forceinline__ float sigm_f(float x) {
  return __builtin_amdgcn_rcpf(1.f + __expf(-x));
}
__device__ __forceinline__ float tanh_f(float x) {
  return 1.f - 2.f * __builtin_amdgcn_rcpf(1.f + __expf(2.f * x));
}

#define MFMA16(a, b, c) __builtin_amdgcn_mfma_f32_16x16x32_bf16((a), (b), (c), 0, 0, 0)

// Layouts (v_mfma_f32_16x16x32_bf16):
//   A (16x32): row = lane&15, k = (lane>>4)*8 + j
//   B (32x16): col = lane&15, k = (lane>>4)*8 + j
//   D (16x16): col = lane&15, row = (lane>>4)*4 + r   [m89-verified]
// Lane l: batch n=l&3, slot j=(l>>2)&3, hid = wave*16+(l>>4)*4+j.
// h_lds stride 144 bf16 (288B): b128 chunk bank = (8n+4kgrp)%32 -> 2-way (free, m136).
// h write: shfl_xor(4) pair-pack -> b32 by even-j lanes, all 32 banks distinct.
// Model (r5): step time was 64 MFMA/SIMD x 19.4cyc = 1242cyc (MfmaUtil-exact).
// This round: single-bf16 W (no lo-split) halves the MFMA pipe load.
__global__ __launch_bounds__(512, 2)
void lstm_bkt_kernel(const float* __restrict__ x, const float* __restrict__ y,
                     const float* __restrict__ W_ih, const float* __restrict__ W_hh,
                     const float* __restrict__ b_ih, const float* __restrict__ b_hh,
                     const float* __restrict__ prior_W, const float* __restrict__ prior_b,
                     const float* __restrict__ post_W, const float* __restrict__ post_b,
                     float* __restrict__ out)
{
  __shared__ __align__(16) __bf16 h_lds[2][NB][144];           // 144 = 128 + 16 pad
  __shared__ __align__(16) float  x_lds[T_STEPS][NB];
  __shared__ __align__(16) float  params_lds[T_STEPS][NB][4];  // logits -> sigmoid -> corrects
  __shared__ float wsums[NWAVE];

  const int tid  = threadIdx.x;
  const int wave = tid >> 6;
  const int lane = tid & 63;
  const int b0   = blockIdx.x * NB;

  // stage x for this block's batch lanes
  for (int idx = tid; idx < T_STEPS * NB; idx += 512) {
    x_lds[idx >> 2][idx & 3] = x[(idx >> 2) * B_TOT + b0 + (idx & 3)];
  }

  const int arow = lane & 15;
  const int kgrp = lane >> 4;

  // W_hh register-resident A-fragments, single bf16 (RNE).
  bf16x8 a_w[4][4];
#pragma unroll
  for (int q = 0; q < 4; ++q) {
#pragma unroll
    for (int kt = 0; kt < 4; ++kt) {
      const float* p = W_hh + (q * HID + wave * 16 + arow) * HID + kt * 32 + kgrp * 8;
      f32x4 v0 = *(const f32x4*)(p);
      f32x4 v1 = *(const f32x4*)(p + 4);
      bf16x8 w;
#pragma unroll
      for (int j = 0; j < 4; ++j) {
        w[j]     = (__bf16)v0[j];
        w[4 + j] = (__bf16)v1[j];
      }
      a_w[q][kt] = w;
    }
  }

  // post_W (4x128) as a 5th M-tile (rows 0..3 valid). Wave 7 only.
  bf16x8 ap[4];
#pragma unroll
  for (int kt = 0; kt < 4; ++kt) {
    bf16x8 v;
#pragma unroll
    for (int j = 0; j < 8; ++j) v[j] = (__bf16)0.f;
    if (arow < 4) {
      const float* p = post_W + arow * HID + kt * 32 + kgrp * 8;
#pragma unroll
      for (int j = 0; j < 8; ++j) v[j] = (__bf16)p[j];
    }
    ap[kt] = v;
  }

  // epilogue assignment (one (batch,hid) per lane)
  const int n_l   = lane & 3;
  const int j_l   = (lane >> 2) & 3;
  const int hid_l = wave * 16 + kgrp * 4 + j_l;
  float wih[4], bias[4];
#pragma unroll
  for (int q = 0; q < 4; ++q) {
    wih[q]  = W_ih[q * HID + hid_l];
    bias[q] = b_ih[q * HID + hid_l] + b_hh[q * HID + hid_l];
  }

  // double-buffer LDS pointers (swapped per iter; no per-iter address rebuild)
  const __bf16* rb   = &h_lds[1][n_l][kgrp * 8];   // k=1 reads buf1 (h_1)
  const __bf16* rb_n = &h_lds[0][n_l][kgrp * 8];
  __bf16* wb   = &h_lds[0][n_l][hid_l];            // k=1 writes h_2 -> buf0
  __bf16* wb_n = &h_lds[1][n_l][hid_l];

  const f32x4 fzero = {0.f, 0.f, 0.f, 0.f};
  float c_state;

  __syncthreads();

  // ---- k = 0 (peeled): h_0 = 0, gates = x*wih + bias only ----
  {
    const float xv = x_lds[0][n_l];
    float g_i = xv * wih[0] + bias[0];
    float g_f = xv * wih[1] + bias[1];
    float g_g = xv * wih[2] + bias[2];
    float g_o = xv * wih[3] + bias[3];
    (void)g_f;                                   // f-gate * c_0(=0) drops out
    c_state = sigm_f(g_i) * tanh_f(g_g);
    float h = sigm_f(g_o) * tanh_f(c_state);
    unsigned hv = (unsigned)__builtin_bit_cast(unsigned short, (__bf16)h);
    unsigned pv = (unsigned)__shfl_xor((int)hv, 4, 64);
    if ((j_l & 1) == 0) *(unsigned*)wb_n = hv | (pv << 16);   // h_1 -> buf1
  }
  __syncthreads();

  // ---- main loop k = 1..511: MFMA(h_k) + epilogue -> h_{k+1} ----
  for (int k = 1; k < T_STEPS; ++k) {
    bf16x8 bfr0 = *(const bf16x8*)(rb);
    bf16x8 bfr1 = *(const bf16x8*)(rb + 32);
    bf16x8 bfr2 = *(const bf16x8*)(rb + 64);
    bf16x8 bfr3 = *(const bf16x8*)(rb + 96);

    f32x4 a0 = MFMA16(a_w[0][0], bfr0, fzero);
    f32x4 a1 = MFMA16(a_w[1][0], bfr0, fzero);
    f32x4 a2 = MFMA16(a_w[2][0], bfr0, fzero);
    f32x4 a3 = MFMA16(a_w[3][0], bfr0, fzero);
    a0 = MFMA16(a_w[0][1], bfr1, a0);
    a1 = MFMA16(a_w[1][1], bfr1, a1);
    a2 = MFMA16(a_w[2][1], bfr1, a2);
    a3 = MFMA16(a_w[3][1], bfr1, a3);
    a0 = MFMA16(a_w[0][2], bfr2, a0);
    a1 = MFMA16(a_w[1][2], bfr2, a1);
    a2 = MFMA16(a_w[2][2], bfr2, a2);
    a3 = MFMA16(a_w[3][2], bfr2, a3);
    a0 = MFMA16(a_w[0][3], bfr3, a0);
    a1 = MFMA16(a_w[1][3], bfr3, a1);
    a2 = MFMA16(a_w[2][3], bfr3, a2);
    a3 = MFMA16(a_w[3][3], bfr3, a3);

    if (wave == 7) {
      f32x4 accp = MFMA16(ap[0], bfr0, fzero);
      accp = MFMA16(ap[1], bfr1, accp);
      accp = MFMA16(ap[2], bfr2, accp);
      accp = MFMA16(ap[3], bfr3, accp);
      if (lane < 4) *(f32x4*)&params_lds[k - 1][lane][0] = accp;  // post_W@h_k
    }

    // epilogue: static-index select on j_l (rule #20 safe)
    float g_i = (j_l == 0) ? a0[0] : (j_l == 1) ? a0[1] : (j_l == 2) ? a0[2] : a0[3];
    float g_f = (j_l == 0) ? a1[0] : (j_l == 1) ? a1[1] : (j_l == 2) ? a1[2] : a1[3];
    float g_g = (j_l == 0) ? a2[0] : (j_l == 1) ? a2[1] : (j_l == 2) ? a2[2] : a2[3];
    float g_o = (j_l == 0) ? a3[0] : (j_l == 1) ? a3[1] : (j_l == 2) ? a3[2] : a3[3];
    const float xv = x_lds[k][n_l];
    g_i += xv * wih[0] + bias[0];
    g_f += xv * wih[1] + bias[1];
    g_g += xv * wih[2] + bias[2];
    g_o += xv * wih[3] + bias[3];
    float is = sigm_f(g_i), fs = sigm_f(g_f), gt = tanh_f(g_g), os = sigm_f(g_o);
    c_state = fs * c_state + is * gt;
    float h = os * tanh_f(c_state);
    unsigned hv = (unsigned)__builtin_bit_cast(unsigned short, (__bf16)h);
    unsigned pv = (unsigned)__shfl_xor((int)hv, 4, 64);
    if ((j_l & 1) == 0) *(unsigned*)wb = hv | (pv << 16);

    __syncthreads();
    const __bf16* tr = rb; rb = rb_n; rb_n = tr;
    __bf16* tw = wb; wb = wb_n; wb_n = tw;
  }

  // ---- k = 512 (peeled): params[511] = post_W @ h_512 ----
  if (wave == 7) {
    bf16x8 bfr0 = *(const bf16x8*)(rb);
    bf16x8 bfr1 = *(const bf16x8*)(rb + 32);
    bf16x8 bfr2 = *(const bf16x8*)(rb + 64);
    bf16x8 bfr3 = *(const bf16x8*)(rb + 96);
    f32x4 accp = MFMA16(ap[0], bfr0, fzero);
    accp = MFMA16(ap[1], bfr1, accp);
    accp = MFMA16(ap[2], bfr2, accp);
    accp = MFMA16(ap[3], bfr3, accp);
    if (lane < 4) *(f32x4*)&params_lds[T_STEPS - 1][lane][0] = accp;
  }
  __syncthreads();

  // params: + post_b, sigmoid
  {
    const float pb0 = post_b[0], pb1 = post_b[1], pb2 = post_b[2], pb3 = post_b[3];
    float* pl = &params_lds[0][0][0];
    for (int idx = tid; idx < T_STEPS * NB * 4; idx += 512) {
      const int p = idx & 3;
      const float pb = (p == 0) ? pb0 : (p == 1) ? pb1 : (p == 2) ? pb2 : pb3;
      pl[idx] = sigm_f(pl[idx] + pb);
    }
  }
  __syncthreads();

  // BKT scan: m_t == latent algebraically -> affine recursion:
  //   correct = L*(1-s-g)+g ;  next_L = L*(1-f-l)+l
  if (tid < NB) {
    const int n = tid;
    float L = sigm_f(x_lds[0][n] * prior_W[0] + prior_b[0]);
    float* cor_out = out;
    float* lat_out = out + T_STEPS * B_TOT;
    for (int t = 0; t < T_STEPS; ++t) {
      f32x4 p = *(const f32x4*)&params_lds[t][n][0];   // l,f,g,s
      float corr = L * (1.f - p[3] - p[2]) + p[2];
      float nL   = L * (1.f - p[1] - p[0]) + p[0];
      cor_out[t * B_TOT + b0 + n] = corr;
      lat_out[t * B_TOT + b0 + n] = nL;
      params_lds[t][n][0] = corr;                      // stash for BCE
      L = nL;
    }
  }
  __syncthreads();

  // BCE loss: parallel over (t,n), block-reduce, one atomic per block
  float lsum = 0.f;
  for (int idx = tid; idx < T_STEPS * NB; idx += 512) {
    const int t = idx >> 2, n = idx & 3;
    const float corr = params_lds[t][n][0];
    const float yv = y[t * B_TOT + b0 + n];
    const float lc  = fmaxf(__logf(corr), -100.f);
    const float lc1 = fmaxf(__logf(1.f - corr), -100.f);
    lsum -= yv * lc + (1.f - yv) * lc1;
  }
#pragma unroll
  for (int off = 32; off > 0; off >>= 1) lsum += __shfl_down(lsum, off, 64);
  if (lane == 0) wsums[wave] = lsum;
  __syncthreads();
  if (tid == 0) {
    float s = 0.f;
#pragma unroll
    for (int w = 0; w < NWAVE; ++w) s += wsums[w];
    atomicAdd(out + 2 * T_STEPS * B_TOT, s * (1.f / (float)(T_STEPS * B_TOT)));
  }
}

__global__ void loss_init_kernel(float* out) {
  out[2 * T_STEPS * B_TOT] = 0.f;
}

extern "C" void kernel_launch(void* const* d_in, const int* in_sizes, int n_in,
                              void* d_out, int out_size, void* d_ws, size_t ws_size,
                              hipStream_t stream) {
  (void)in_sizes; (void)n_in; (void)out_size; (void)d_ws; (void)ws_size;
  const float* x       = (const float*)d_in[0];
  const float* y       = (const float*)d_in[1];
  const float* W_ih    = (const float*)d_in[2];
  const float* W_hh    = (const float*)d_in[3];
  const float* b_ih    = (const float*)d_in[4];
  const float* b_hh    = (const float*)d_in[5];
  const float* prior_W = (const float*)d_in[6];
  const float* prior_b = (const float*)d_in[7];
  const float* post_W  = (const float*)d_in[8];
  const float* post_b  = (const float*)d_in[9];
  float* out = (float*)d_out;

  loss_init_kernel<<<dim3(1), dim3(1), 0, stream>>>(out);
  lstm_bkt_kernel<<<dim3(B_TOT / NB), dim3(512), 0, stream>>>(
      x, y, W_ih, W_hh, b_ih, b_hh, prior_W, prior_b, post_W, post_b, out);
}

// Round 11
// 412.999 us; speedup vs baseline: 1.5369x; 1.0114x over previous
//
#include <hip/hip_runtime.h>

#define T_STEPS 512
#define B_TOT   1024
#define HID     128
#define NB      4      // batch lanes per block
#define NWAVE   8

typedef __bf16 bf16x8 __attribute__((ext_vector_type(8)));
typedef float  f32x4  __attribute__((ext_vector_type(4)));

__device__ __forceinline__ float sigm_f(float x) {
  return __builtin_amdgcn_rcpf(1.f + __expf(-x));
}
__device__ __forceinline__ float tanh_f(float x) {
  return 1.f - 2.f * __builtin_amdgcn_rcpf(1.f + __expf(2.f * x));
}

#define MFMA16(a, b, c) __builtin_amdgcn_mfma_f32_16x16x32_bf16((a), (b), (c), 0, 0, 0)

// Layouts (v_mfma_f32_16x16x32_bf16):
//   A (16x32): row = lane&15, k = (lane>>4)*8 + j
//   B (32x16): col = lane&15, k = (lane>>4)*8 + j
//   D (16x16): col = lane&15, row = (lane>>4)*4 + r   [m89-verified]
// Lane l: batch n=l&3, slot j=(l>>2)&3, hid = wave*16+(l>>4)*4+j.
// h_lds stride 144 bf16 (288B): b128 chunk bank = (8n+4kgrp)%32 -> 2-way (free, m136).
// h write: shfl_xor(4) pair-pack -> b32 by even-j lanes, all 32 banks distinct.
// Model (r8): step = MFMA phase (570cyc pipe) + epilogue (730cyc VALU) mostly
// DISJOINT. This round: acc-major MFMA chains with per-gate epilogue interleave
// so transcendentals run under the matrix pipe; params MFMA round-robined.
__global__ __launch_bounds__(512, 2)
void lstm_bkt_kernel(const float* __restrict__ x, const float* __restrict__ y,
                     const float* __restrict__ W_ih, const float* __restrict__ W_hh,
                     const float* __restrict__ b_ih, const float* __restrict__ b_hh,
                     const float* __restrict__ prior_W, const float* __restrict__ prior_b,
                     const float* __restrict__ post_W, const float* __restrict__ post_b,
                     float* __restrict__ out)
{
  __shared__ __align__(16) __bf16 h_lds[2][NB][144];           // 144 = 128 + 16 pad
  __shared__ __align__(16) float  x_lds[T_STEPS][NB];
  __shared__ __align__(16) float  params_lds[T_STEPS][NB][4];  // logits -> sigmoid -> corrects
  __shared__ float wsums[NWAVE];

  const int tid  = threadIdx.x;
  const int wave = tid >> 6;
  const int lane = tid & 63;
  const int b0   = blockIdx.x * NB;

  // stage x for this block's batch lanes
  for (int idx = tid; idx < T_STEPS * NB; idx += 512) {
    x_lds[idx >> 2][idx & 3] = x[(idx >> 2) * B_TOT + b0 + (idx & 3)];
  }

  const int arow = lane & 15;
  const int kgrp = lane >> 4;

  // W_hh register-resident A-fragments, single bf16 (RNE).
  bf16x8 a_w[4][4];
#pragma unroll
  for (int q = 0; q < 4; ++q) {
#pragma unroll
    for (int kt = 0; kt < 4; ++kt) {
      const float* p = W_hh + (q * HID + wave * 16 + arow) * HID + kt * 32 + kgrp * 8;
      f32x4 v0 = *(const f32x4*)(p);
      f32x4 v1 = *(const f32x4*)(p + 4);
      bf16x8 w;
#pragma unroll
      for (int j = 0; j < 4; ++j) {
        w[j]     = (__bf16)v0[j];
        w[4 + j] = (__bf16)v1[j];
      }
      a_w[q][kt] = w;
    }
  }

  // post_W (4x128) as a 5th M-tile (rows 0..3 valid). All waves load (round-robin use).
  bf16x8 ap[4];
#pragma unroll
  for (int kt = 0; kt < 4; ++kt) {
    bf16x8 v;
#pragma unroll
    for (int j = 0; j < 8; ++j) v[j] = (__bf16)0.f;
    if (arow < 4) {
      const float* p = post_W + arow * HID + kt * 32 + kgrp * 8;
#pragma unroll
      for (int j = 0; j < 8; ++j) v[j] = (__bf16)p[j];
    }
    ap[kt] = v;
  }

  // epilogue assignment (one (batch,hid) per lane)
  const int n_l   = lane & 3;
  const int j_l   = (lane >> 2) & 3;
  const int hid_l = wave * 16 + kgrp * 4 + j_l;
  float wih[4], bias[4];
#pragma unroll
  for (int q = 0; q < 4; ++q) {
    wih[q]  = W_ih[q * HID + hid_l];
    bias[q] = b_ih[q * HID + hid_l] + b_hh[q * HID + hid_l];
  }

  // double-buffer LDS pointers (swapped per iter)
  const __bf16* rb   = &h_lds[1][n_l][kgrp * 8];   // k=1 reads buf1 (h_1)
  const __bf16* rb_n = &h_lds[0][n_l][kgrp * 8];
  __bf16* wb   = &h_lds[0][n_l][hid_l];            // k=1 writes h_2 -> buf0
  __bf16* wb_n = &h_lds[1][n_l][hid_l];

  const f32x4 fzero = {0.f, 0.f, 0.f, 0.f};
  float c_state;

  __syncthreads();

  // ---- k = 0 (peeled): h_0 = 0, gates = x*wih + bias only ----
  {
    const float xv = x_lds[0][n_l];
    float g_i = fmaf(xv, wih[0], bias[0]);
    float g_g = fmaf(xv, wih[2], bias[2]);
    float g_o = fmaf(xv, wih[3], bias[3]);
    c_state = sigm_f(g_i) * tanh_f(g_g);
    float h = sigm_f(g_o) * tanh_f(c_state);
    unsigned hv = (unsigned)__builtin_bit_cast(unsigned short, (__bf16)h);
    unsigned pv = (unsigned)__shfl_xor((int)hv, 4, 64);
    if ((j_l & 1) == 0) *(unsigned*)wb_n = hv | (pv << 16);   // h_1 -> buf1
  }
  __syncthreads();

  // ---- main loop k = 1..511 ----
  for (int k = 1; k < T_STEPS; ++k) {
    // x-part of gates: independent of h, fills ds_read latency
    const float xv = x_lds[k][n_l];
    const float gx_i = fmaf(xv, wih[0], bias[0]);
    const float gx_f = fmaf(xv, wih[1], bias[1]);
    const float gx_g = fmaf(xv, wih[2], bias[2]);
    const float gx_o = fmaf(xv, wih[3], bias[3]);

    bf16x8 bfr0 = *(const bf16x8*)(rb);
    bf16x8 bfr1 = *(const bf16x8*)(rb + 32);
    bf16x8 bfr2 = *(const bf16x8*)(rb + 64);
    bf16x8 bfr3 = *(const bf16x8*)(rb + 96);

    // acc-major: finish gate i's chain, start its transcendental under the
    // remaining chains' pipe time. Chain order per acc unchanged (bit-exact).
    f32x4 a0 = MFMA16(a_w[0][0], bfr0, fzero);
    a0 = MFMA16(a_w[0][1], bfr1, a0);
    a0 = MFMA16(a_w[0][2], bfr2, a0);
    a0 = MFMA16(a_w[0][3], bfr3, a0);
    float g_i = ((j_l == 0) ? a0[0] : (j_l == 1) ? a0[1] : (j_l == 2) ? a0[2] : a0[3]) + gx_i;
    float is = sigm_f(g_i);

    f32x4 a1 = MFMA16(a_w[1][0], bfr0, fzero);
    a1 = MFMA16(a_w[1][1], bfr1, a1);
    a1 = MFMA16(a_w[1][2], bfr2, a1);
    a1 = MFMA16(a_w[1][3], bfr3, a1);
    float g_f = ((j_l == 0) ? a1[0] : (j_l == 1) ? a1[1] : (j_l == 2) ? a1[2] : a1[3]) + gx_f;
    float fs = sigm_f(g_f);

    f32x4 a2 = MFMA16(a_w[2][0], bfr0, fzero);
    a2 = MFMA16(a_w[2][1], bfr1, a2);
    a2 = MFMA16(a_w[2][2], bfr2, a2);
    a2 = MFMA16(a_w[2][3], bfr3, a2);
    float g_g = ((j_l == 0) ? a2[0] : (j_l == 1) ? a2[1] : (j_l == 2) ? a2[2] : a2[3]) + gx_g;
    float gt = tanh_f(g_g);

    f32x4 a3 = MFMA16(a_w[3][0], bfr0, fzero);
    a3 = MFMA16(a_w[3][1], bfr1, a3);
    a3 = MFMA16(a_w[3][2], bfr2, a3);
    a3 = MFMA16(a_w[3][3], bfr3, a3);
    float g_o = ((j_l == 0) ? a3[0] : (j_l == 1) ? a3[1] : (j_l == 2) ? a3[2] : a3[3]) + gx_o;
    float os = sigm_f(g_o);

    c_state = fmaf(fs, c_state, is * gt);
    float h = os * tanh_f(c_state);
    unsigned hv = (unsigned)__builtin_bit_cast(unsigned short, (__bf16)h);
    unsigned pv = (unsigned)__shfl_xor((int)hv, 4, 64);
    if ((j_l & 1) == 0) *(unsigned*)wb = hv | (pv << 16);

    // params MFMA: round-robin wave (no straggler SIMD); overlaps others' epilogue
    if (wave == (k & 7)) {
      f32x4 accp = MFMA16(ap[0], bfr0, fzero);
      accp = MFMA16(ap[1], bfr1, accp);
      accp = MFMA16(ap[2], bfr2, accp);
      accp = MFMA16(ap[3], bfr3, accp);
      if (lane < 4) *(f32x4*)&params_lds[k - 1][lane][0] = accp;  // post_W@h_k
    }

    __syncthreads();
    const __bf16* tr = rb; rb = rb_n; rb_n = tr;
    __bf16* tw = wb; wb = wb_n; wb_n = tw;
  }

  // ---- k = 512 (peeled): params[511] = post_W @ h_512 (wave T_STEPS&7 = 0) ----
  if (wave == (T_STEPS & 7)) {
    bf16x8 bfr0 = *(const bf16x8*)(rb);
    bf16x8 bfr1 = *(const bf16x8*)(rb + 32);
    bf16x8 bfr2 = *(const bf16x8*)(rb + 64);
    bf16x8 bfr3 = *(const bf16x8*)(rb + 96);
    f32x4 accp = MFMA16(ap[0], bfr0, fzero);
    accp = MFMA16(ap[1], bfr1, accp);
    accp = MFMA16(ap[2], bfr2, accp);
    accp = MFMA16(ap[3], bfr3, accp);
    if (lane < 4) *(f32x4*)&params_lds[T_STEPS - 1][lane][0] = accp;
  }
  __syncthreads();

  // params: + post_b, sigmoid
  {
    const float pb0 = post_b[0], pb1 = post_b[1], pb2 = post_b[2], pb3 = post_b[3];
    float* pl = &params_lds[0][0][0];
    for (int idx = tid; idx < T_STEPS * NB * 4; idx += 512) {
      const int p = idx & 3;
      const float pb = (p == 0) ? pb0 : (p == 1) ? pb1 : (p == 2) ? pb2 : pb3;
      pl[idx] = sigm_f(pl[idx] + pb);
    }
  }
  __syncthreads();

  // BKT scan: m_t == latent algebraically -> affine recursion:
  //   correct = L*(1-s-g)+g ;  next_L = L*(1-f-l)+l
  if (tid < NB) {
    const int n = tid;
    float L = sigm_f(x_lds[0][n] * prior_W[0] + prior_b[0]);
    float* cor_out = out;
    float* lat_out = out + T_STEPS * B_TOT;
    for (int t = 0; t < T_STEPS; ++t) {
      f32x4 p = *(const f32x4*)&params_lds[t][n][0];   // l,f,g,s
      float corr = L * (1.f - p[3] - p[2]) + p[2];
      float nL   = L * (1.f - p[1] - p[0]) + p[0];
      cor_out[t * B_TOT + b0 + n] = corr;
      lat_out[t * B_TOT + b0 + n] = nL;
      params_lds[t][n][0] = corr;                      // stash for BCE
      L = nL;
    }
  }
  __syncthreads();

  // BCE loss: parallel over (t,n), block-reduce, one atomic per block
  float lsum = 0.f;
  for (int idx = tid; idx < T_STEPS * NB; idx += 512) {
    const int t = idx >> 2, n = idx & 3;
    const float corr = params_lds[t][n][0];
    const float yv = y[t * B_TOT + b0 + n];
    const float lc  = fmaxf(__logf(corr), -100.f);
    const float lc1 = fmaxf(__logf(1.f - corr), -100.f);
    lsum -= yv * lc + (1.f - yv) * lc1;
  }
#pragma unroll
  for (int off = 32; off > 0; off >>= 1) lsum += __shfl_down(lsum, off, 64);
  if (lane == 0) wsums[wave] = lsum;
  __syncthreads();
  if (tid == 0) {
    float s = 0.f;
#pragma unroll
    for (int w = 0; w < NWAVE; ++w) s += wsums[w];
    atomicAdd(out + 2 * T_STEPS * B_TOT, s * (1.f / (float)(T_STEPS * B_TOT)));
  }
}

__global__ void loss_init_kernel(float* out) {
  out[2 * T_STEPS * B_TOT] = 0.f;
}

extern "C" void kernel_launch(void* const* d_in, const int* in_sizes, int n_in,
                              void* d_out, int out_size, void* d_ws, size_t ws_size,
                              hipStream_t stream) {
  (void)in_sizes; (void)n_in; (void)out_size; (void)d_ws; (void)ws_size;
  const float* x       = (const float*)d_in[0];
  const float* y       = (const float*)d_in[1];
  const float* W_ih    = (const float*)d_in[2];
  const float* W_hh    = (const float*)d_in[3];
  const float* b_ih    = (const float*)d_in[4];
  const float* b_hh    = (const float*)d_in[5];
  const float* prior_W = (const float*)d_in[6];
  const float* prior_b = (const float*)d_in[7];
  const float* post_W  = (const float*)d_in[8];
  const float* post_b  = (const float*)d_in[9];
  float* out = (float*)d_out;

  loss_init_kernel<<<dim3(1), dim3(1), 0, stream>>>(out);
  lstm_bkt_kernel<<<dim3(B_TOT / NB), dim3(512), 0, stream>>>(
      x, y, W_ih, W_hh, b_ih, b_hh, prior_W, prior_b, post_W, post_b, out);
}